// Round 1
// baseline (924.912 us; speedup 1.0000x reference)
//
#include <hip/hip_runtime.h>
#include <stdint.h>

#define IN_DIM    1024
#define OUT_DIM   1024
#define ROWSTRIDE 1025        // x has INPUT_DIM + CONDITION_DIM columns
#define BATCH     32768
#define NBASIS    6
#define KTOT      (NBASIS * IN_DIM)   // 6144

typedef __bf16 bf16x8 __attribute__((ext_vector_type(8)));
typedef float  f32x4  __attribute__((ext_vector_type(4)));

__device__ inline unsigned short f2bf(float f) {
  union { float f; unsigned u; } v; v.f = f;
  unsigned u = v.u;
  return (unsigned short)((u + 0x7FFFu + ((u >> 16) & 1u)) >> 16);  // RNE
}

// ---------- prep 1: feats fp32 -> bf16 [BATCH][1024] ----------
__global__ void prep_feats(const float* __restrict__ x, unsigned short* __restrict__ A) {
  int idx = blockIdx.x * 256 + threadIdx.x;
  if (idx < BATCH * IN_DIM) {
    int b = idx >> 10, d = idx & 1023;
    A[idx] = f2bf(x[(size_t)b * ROWSTRIDE + d]);
  }
}

// ---------- prep 2: weight [6144][1024] fp32 -> BT [1024][6144] bf16 ----------
__global__ void prep_wt(const float* __restrict__ w, unsigned short* __restrict__ bt) {
  __shared__ unsigned short t[32][33];
  int k0 = blockIdx.x * 32;   // over KTOT
  int e0 = blockIdx.y * 32;   // over OUT_DIM
  int tid = threadIdx.x;      // 256
  #pragma unroll
  for (int p = tid; p < 1024; p += 256) {
    int kk = p >> 5, ee = p & 31;                       // coalesced read over ee
    t[ee][kk] = f2bf(w[(size_t)(k0 + kk) * OUT_DIM + e0 + ee]);
  }
  __syncthreads();
  #pragma unroll
  for (int p = tid; p < 1024; p += 256) {
    int ee = p >> 5, kk = p & 31;                       // coalesced write over kk
    bt[(size_t)(e0 + ee) * KTOT + k0 + kk] = t[ee][kk];
  }
}

// ---------- GEMM ----------
__device__ inline void gload_lds16(const unsigned short* g, unsigned short* l) {
  __builtin_amdgcn_global_load_lds((const __attribute__((address_space(1))) void*)g,
                                   (__attribute__((address_space(3))) void*)l, 16, 0, 0);
}

__global__ __launch_bounds__(256, 2) void vcl_gemm(
    const unsigned short* __restrict__ A,    // [BATCH][1024] bf16 feats
    const unsigned short* __restrict__ BT,   // [1024][6144] bf16 W^T (n-major, k contiguous)
    const float* __restrict__ x,             // condition source
    const float* __restrict__ bias,
    float* __restrict__ out) {
  // LDS tiles, XOR-swizzled: slot (r, cs) holds k-chunk cs ^ (r&7); chunk = 8 bf16 = 16 B
  __shared__ unsigned short sA[128 * 64];
  __shared__ unsigned short sB[128 * 64];
  __shared__ float basisS[128][NBASIS];

  const int tid = threadIdx.x;
  const int bm0 = (blockIdx.x >> 3) * 128;
  const int bn0 = (blockIdx.x & 7) * 128;

  if (tid < 128) {  // per-row basis table (rows fixed for whole block)
    float t = x[(size_t)(bm0 + tid) * ROWSTRIDE + IN_DIM];
    basisS[tid][0] = 1.0f;
    basisS[tid][1] = t;
    basisS[tid][2] = t * t;
    float r1 = fmaxf(t - 0.25f, 0.0f);
    float r2 = fmaxf(t - 0.50f, 0.0f);
    float r3 = fmaxf(t - 0.75f, 0.0f);
    basisS[tid][3] = r1 * r1;
    basisS[tid][4] = r2 * r2;
    basisS[tid][5] = r3 * r3;
  }

  const int wv   = tid >> 6;
  const int lane = tid & 63;
  const int lr   = lane >> 3;          // row within 8-row staging chunk
  const int kc   = (lane & 7) ^ lr;    // swizzled global k-chunk for this lane
  const int ln15 = lane & 15;
  const int quad = lane >> 4;
  const int wm   = wv >> 1, wn = wv & 1;

  // staging address bases (4 wave-instructions each for A and B per k-step)
  const unsigned short* gA[4];
  const unsigned short* gB[4];
  unsigned short* lA[4];
  unsigned short* lB[4];
  #pragma unroll
  for (int wc = 0; wc < 4; ++wc) {
    int r = wv * 32 + wc * 8 + lr;
    gA[wc] = A  + (size_t)(bm0 + r) * IN_DIM + kc * 8;
    gB[wc] = BT + (size_t)(bn0 + r) * KTOT   + kc * 8;
    lA[wc] = sA + (wv * 4 + wc) * 512;   // 1024 B per wave-instruction, lane*16 inside
    lB[wc] = sB + (wv * 4 + wc) * 512;
  }

  f32x4 acc[4][4] = {};

  for (int c = 0; c < NBASIS; ++c) {
    f32x4 seg[4][4] = {};
    for (int t = 0; t < 16; ++t) {
      const int kA = t * 64;                 // A is 1024-wide (per-segment)
      const int kB = (c * 16 + t) * 64;      // BT is 6144-wide
      __syncthreads();
      #pragma unroll
      for (int wc = 0; wc < 4; ++wc) {
        gload_lds16(gA[wc] + kA, lA[wc]);
        gload_lds16(gB[wc] + kB, lB[wc]);
      }
      __syncthreads();
      #pragma unroll
      for (int ks = 0; ks < 2; ++ks) {
        bf16x8 af[4], bfr[4];
        const int ck = ks * 4 + quad;        // k-chunk this quad needs
        const int cs = ck ^ (ln15 & 7);      // swizzled slot (row&7 == ln15&7)
        #pragma unroll
        for (int i = 0; i < 4; ++i) {
          int rowt = wm * 64 + i * 16 + ln15;
          af[i]  = *(const bf16x8*)(sA + rowt * 64 + cs * 8);
          int nt = wn * 64 + i * 16 + ln15;
          bfr[i] = *(const bf16x8*)(sB + nt * 64 + cs * 8);
        }
        #pragma unroll
        for (int i = 0; i < 4; ++i)
          #pragma unroll
          for (int j = 0; j < 4; ++j)
            seg[i][j] = __builtin_amdgcn_mfma_f32_16x16x32_bf16(af[i], bfr[j], seg[i][j], 0, 0, 0);
      }
    }
    // fold segment: acc += basis[row, c] * seg   (C/D layout: col=lane&15, row=quad*4+reg)
    #pragma unroll
    for (int i = 0; i < 4; ++i) {
      int rbase = wm * 64 + i * 16 + quad * 4;
      float b0 = basisS[rbase + 0][c];
      float b1 = basisS[rbase + 1][c];
      float b2 = basisS[rbase + 2][c];
      float b3 = basisS[rbase + 3][c];
      #pragma unroll
      for (int j = 0; j < 4; ++j) {
        acc[i][j][0] += b0 * seg[i][j][0];
        acc[i][j][1] += b1 * seg[i][j][1];
        acc[i][j][2] += b2 * seg[i][j][2];
        acc[i][j][3] += b3 * seg[i][j][3];
      }
    }
  }

  // epilogue: + bias, fp32 store
  #pragma unroll
  for (int i = 0; i < 4; ++i) {
    int row0 = bm0 + wm * 64 + i * 16 + quad * 4;
    #pragma unroll
    for (int j = 0; j < 4; ++j) {
      int col = bn0 + wn * 64 + j * 16 + ln15;
      float bv = bias[col];
      #pragma unroll
      for (int r = 0; r < 4; ++r)
        out[(size_t)(row0 + r) * OUT_DIM + col] = acc[i][j][r] + bv;
    }
  }
}

extern "C" void kernel_launch(void* const* d_in, const int* in_sizes, int n_in,
                              void* d_out, int out_size, void* d_ws, size_t ws_size,
                              hipStream_t stream) {
  const float* x    = (const float*)d_in[0];
  const float* w    = (const float*)d_in[1];
  const float* bias = (const float*)d_in[2];
  float* out = (float*)d_out;

  // ws layout: A' bf16 [32768][1024] = 64 MiB, then BT bf16 [1024][6144] = 12 MiB
  unsigned short* A  = (unsigned short*)d_ws;
  unsigned short* BT = (unsigned short*)((char*)d_ws + (size_t)BATCH * IN_DIM * 2);

  prep_feats<<<(BATCH * IN_DIM) / 256, 256, 0, stream>>>(x, A);
  dim3 g2(KTOT / 32, OUT_DIM / 32);
  prep_wt<<<g2, 256, 0, stream>>>(w, BT);
  vcl_gemm<<<(BATCH / 128) * (OUT_DIM / 128), 256, 0, stream>>>(A, BT, x, bias, out);
}